// Round 1
// baseline (196.264 us; speedup 1.0000x reference)
//
#include <hip/hip_runtime.h>
#include <hip/hip_cooperative_groups.h>
#include <math.h>

namespace cg = cooperative_groups;

// Problem constants (from reference setup_inputs): B=8, C=3, H=W=1024, K=128.
// nwr = nwc = ceil((1024-128)/128) = 7; count = 49.
// Only the last window survives: rows/cols [768, 896), reduced over all b,c.
//
// Total live data: 24 images x 128x128 floats x 2 tensors = 3.15 MB -> the
// kernel side is launch-latency bound, not BW bound. rocprof shows the timed
// region is dominated by harness reset fills (~59us @ 85% HBM each); our
// kernels are <=10us combined. Remaining lever: dispatch count. This version
// fuses reduce+finalize into ONE cooperative kernel (96 blocks, all
// co-resident on 256 CUs), eliminating the second launch.

#define NBC     24          // B*C
#define IMG4    262144      // H*W/4 float4 per image
#define ROW4    256         // W/4 float4 per row
#define WIN0_4  192         // 768/4: window column start in float4 units
#define NVEC    (NBC * 128 * 32)  // 98304 float4 across the window region
#define NBLK    96
#define NTHR    256
// NVEC / (NBLK*NTHR) == 4 exactly -> fully unrolled, no bounds check.

__global__ __launch_bounds__(NTHR) void cos_fused(const float4* __restrict__ inp,
                                                  const float4* __restrict__ tar,
                                                  double* __restrict__ partial,
                                                  float* __restrict__ out) {
    double dot = 0.0, ni = 0.0, nt = 0.0;
    const int t0 = blockIdx.x * NTHR + threadIdx.x;
#pragma unroll
    for (int k = 0; k < 4; ++k) {
        int t  = t0 + k * (NBLK * NTHR);
        int w4 = t & 31;            // float4 within the 128-wide window row
        int h  = (t >> 5) & 127;    // row within window
        int bc = t >> 12;           // which (b,c) image
        long idx = (long)bc * IMG4 + (long)(768 + h) * ROW4 + WIN0_4 + w4;
        float4 a = inp[idx];
        float4 b = tar[idx];
        dot += (double)a.x * b.x + (double)a.y * b.y +
               (double)a.z * b.z + (double)a.w * b.w;
        ni  += (double)a.x * a.x + (double)a.y * a.y +
               (double)a.z * a.z + (double)a.w * a.w;
        nt  += (double)b.x * b.x + (double)b.y * b.y +
               (double)b.z * b.z + (double)b.w * b.w;
    }

    // 64-lane wave reduce
    for (int off = 32; off > 0; off >>= 1) {
        dot += __shfl_down(dot, off);
        ni  += __shfl_down(ni,  off);
        nt  += __shfl_down(nt,  off);
    }

    __shared__ double s[3][4];
    {
        int wave = threadIdx.x >> 6;
        int lane = threadIdx.x & 63;
        if (lane == 0) { s[0][wave] = dot; s[1][wave] = ni; s[2][wave] = nt; }
    }
    __syncthreads();
    if (threadIdx.x == 0) {
        double d = 0.0, n1 = 0.0, n2 = 0.0;
        for (int i = 0; i < 4; ++i) { d += s[0][i]; n1 += s[1][i]; n2 += s[2][i]; }
        partial[3 * blockIdx.x + 0] = d;
        partial[3 * blockIdx.x + 1] = n1;
        partial[3 * blockIdx.x + 2] = n2;
        __threadfence();   // device-scope: make partials visible cross-XCD
    }

    cg::this_grid().sync();

    // ---- finalize: block 0 reduces the 96 partial triples ----
    if (blockIdx.x == 0) {
        int tid = threadIdx.x;
        double d = 0.0, n1 = 0.0, n2 = 0.0;
        if (tid < NBLK) {
            d  = partial[3 * tid + 0];
            n1 = partial[3 * tid + 1];
            n2 = partial[3 * tid + 2];
        }
        for (int off = 32; off > 0; off >>= 1) {
            d  += __shfl_down(d,  off);
            n1 += __shfl_down(n1, off);
            n2 += __shfl_down(n2, off);
        }
        int wave = tid >> 6;
        int lane = tid & 63;
        if (lane == 0) { s[0][wave] = d; s[1][wave] = n1; s[2][wave] = n2; }
        __syncthreads();
        if (tid == 0) {
            double dd = 0.0, nn1 = 0.0, nn2 = 0.0;
            for (int i = 0; i < 4; ++i) { dd += s[0][i]; nn1 += s[1][i]; nn2 += s[2][i]; }
            double cosv = dd / (sqrt(nn1) * sqrt(nn2));
            double r = (cosv - 1.0) * (cosv - 1.0) / 49.0;
            out[0] = (float)r;
        }
    }
}

extern "C" void kernel_launch(void* const* d_in, const int* in_sizes, int n_in,
                              void* d_out, int out_size, void* d_ws, size_t ws_size,
                              hipStream_t stream) {
    const float4* inp = (const float4*)d_in[0];
    const float4* tar = (const float4*)d_in[1];
    double* partial = (double*)d_ws;   // 96*3 doubles, write-then-read in-kernel
    float* out = (float*)d_out;

    void* args[] = { (void*)&inp, (void*)&tar, (void*)&partial, (void*)&out };
    hipLaunchCooperativeKernel((const void*)cos_fused, dim3(NBLK), dim3(NTHR),
                               args, 0, stream);
}

// Round 2
// 164.616 us; speedup vs baseline: 1.1922x; 1.1922x over previous
//
#include <hip/hip_runtime.h>
#include <math.h>

// Problem constants (from reference setup_inputs): B=8, C=3, H=W=1024, K=128.
// nwr = nwc = ceil((1024-128)/128) = 7; count = 49.
// Only the last window survives: rows/cols [768, 896), reduced over all b,c.
//
// Total live data: 24 images x 128x128 floats x 2 tensors = 3.15 MB -> the
// kernel side is launch-latency bound, not BW bound. rocprof: timed region is
// dominated by harness reset fills (~59us @ 85% HBM each, WRITE_SIZE fixed);
// our kernels are <=10us combined and never appear in top-5 dispatches.
//
// R1 post-mortem: hipLaunchCooperativeKernel costs ~+35us vs a regular
// graph-captured launch on this harness (165.3 -> 196.3us) -- NEVER trade
// 2 regular launches for 1 cooperative one here. This version reverts to the
// 2-kernel structure and slims finalize to a single 64-lane wave (no LDS,
// no barrier).

#define NBC     24          // B*C
#define IMG4    262144      // H*W/4 float4 per image
#define ROW4    256         // W/4 float4 per row
#define WIN0_4  192         // 768/4: window column start in float4 units
#define NVEC    (NBC * 128 * 32)  // 98304 float4 across the window region
#define NBLK    96

__global__ __launch_bounds__(256) void cos_reduce(const float4* __restrict__ inp,
                                                  const float4* __restrict__ tar,
                                                  double* __restrict__ partial) {
    double dot = 0.0, ni = 0.0, nt = 0.0;
    // NVEC / (NBLK*256) == 4 exactly -> fully unrolled, no bounds check.
    const int t0 = blockIdx.x * 256 + threadIdx.x;
#pragma unroll
    for (int k = 0; k < 4; ++k) {
        int t  = t0 + k * (NBLK * 256);
        int w4 = t & 31;            // float4 within the 128-wide window row
        int h  = (t >> 5) & 127;    // row within window
        int bc = t >> 12;           // which (b,c) image
        long idx = (long)bc * IMG4 + (long)(768 + h) * ROW4 + WIN0_4 + w4;
        float4 a = inp[idx];
        float4 b = tar[idx];
        dot += (double)a.x * b.x + (double)a.y * b.y +
               (double)a.z * b.z + (double)a.w * b.w;
        ni  += (double)a.x * a.x + (double)a.y * a.y +
               (double)a.z * a.z + (double)a.w * a.w;
        nt  += (double)b.x * b.x + (double)b.y * b.y +
               (double)b.z * b.z + (double)b.w * b.w;
    }

    // 64-lane wave reduce
    for (int off = 32; off > 0; off >>= 1) {
        dot += __shfl_down(dot, off);
        ni  += __shfl_down(ni,  off);
        nt  += __shfl_down(nt,  off);
    }

    __shared__ double s[3][4];
    int wave = threadIdx.x >> 6;
    int lane = threadIdx.x & 63;
    if (lane == 0) { s[0][wave] = dot; s[1][wave] = ni; s[2][wave] = nt; }
    __syncthreads();
    if (threadIdx.x == 0) {
        double d = 0.0, n1 = 0.0, n2 = 0.0;
        for (int i = 0; i < 4; ++i) { d += s[0][i]; n1 += s[1][i]; n2 += s[2][i]; }
        partial[3 * blockIdx.x + 0] = d;
        partial[3 * blockIdx.x + 1] = n1;
        partial[3 * blockIdx.x + 2] = n2;
    }
}

// Single-wave finalize: lane i owns partial blocks i and i+64 (96 = 64+32),
// pure shuffle reduce -- no LDS, no __syncthreads.
__global__ __launch_bounds__(64) void cos_finalize(const double* __restrict__ partial,
                                                   float* __restrict__ out) {
    int lane = threadIdx.x;
    double dot = partial[3 * lane + 0];
    double ni  = partial[3 * lane + 1];
    double nt  = partial[3 * lane + 2];
    if (lane < NBLK - 64) {
        dot += partial[3 * (lane + 64) + 0];
        ni  += partial[3 * (lane + 64) + 1];
        nt  += partial[3 * (lane + 64) + 2];
    }
    for (int off = 32; off > 0; off >>= 1) {
        dot += __shfl_down(dot, off);
        ni  += __shfl_down(ni,  off);
        nt  += __shfl_down(nt,  off);
    }
    if (lane == 0) {
        double cosv = dot / (sqrt(ni) * sqrt(nt));
        double r = (cosv - 1.0) * (cosv - 1.0) / 49.0;
        out[0] = (float)r;
    }
}

extern "C" void kernel_launch(void* const* d_in, const int* in_sizes, int n_in,
                              void* d_out, int out_size, void* d_ws, size_t ws_size,
                              hipStream_t stream) {
    const float4* inp = (const float4*)d_in[0];
    const float4* tar = (const float4*)d_in[1];
    double* partial = (double*)d_ws;   // 96*3 doubles, write-only in kernel 1
    float* out = (float*)d_out;

    cos_reduce<<<NBLK, 256, 0, stream>>>(inp, tar, partial);
    cos_finalize<<<1, 64, 0, stream>>>(partial, out);
}